// Round 6
// baseline (179.787 us; speedup 1.0000x reference)
//
#include <hip/hip_runtime.h>
#include <hip/hip_bf16.h>

// FlowNetC correlation via bf16 MFMA, fp32 accumulate.
// out[b, r*21+dx, y, x] = (1/256) * sum_c in1[b,c,y,x] * in2[b,c, y+2r-20, x+2dx-20]
//
// Round-10 structure: NO LDS AT ALL -- direct accumulator stores.
//   Evidence trail: r5 direct-L2 60.5us, r6/r8 LDS-staged 66-67, r9
//   barrier-free 63.6 -- B-path and barriers are NOT the bottleneck; all
//   pipes <28% busy; regs/wave = 128 => 4 waves/SIMD is a hard cap (512-reg
//   file), so more TLP is impossible. Remaining un-ablated phase: the
//   per-iter LDS round-trip (ds_write -> lgkm wait -> ds_read -> store),
//   a ~240cy serial tail on every iteration plus most of the VALU work.
//   This round deletes it: the diagonal ownership is per-lane unique
//   (lane (cl,q), elem i4 owns d2 = 16d+cl-4q-i4, gx = 16m+4q+i4), so each
//   lane stores its own acc elements directly. Store masks and base
//   offsets are loop-invariant (SGPR masks, static indexing); per-iter
//   epilogue = 8 predicated dword stores. Lanes of one d2-row hit the same
//   64B line across the 4 i4-store instructions -> L2 merges full lines.
//   acc==0 when !compute gives zero-fill for free.

typedef short    bf16x8 __attribute__((ext_vector_type(8)));
typedef float    f32x4  __attribute__((ext_vector_type(4)));

constexpr int CSTRIDE = 64 * 64;        // fp32 channel plane
constexpr int BSTRIDE = 256 * CSTRIDE;  // fp32 batch

union BF2 { __hip_bfloat162 h; unsigned u; };

__device__ inline unsigned pack_bf2(float lo, float hi) {
    BF2 cv;
    cv.h = __float22bfloat162_rn(make_float2(lo, hi));
    return cv.u;
}

#define ELT(v4, xi) ((xi) == 0 ? (v4).x : (xi) == 1 ? (v4).y : (xi) == 2 ? (v4).z : (v4).w)

__device__ __align__(16) const uint4 ZERO16 = {0u, 0u, 0u, 0u};

// ---------------- prepass: in2 -> bf16 frag-native chunks ----------------
// 1024 blocks x 256 thr = 16 waves/CU (was 8) for latency hiding.
__global__ __launch_bounds__(256)
void conv_in2(const float* __restrict__ in2, uint4* __restrict__ out16)
{
    const int tid = threadIdx.x;
    const int b  = blockIdx.x & 7;             // XCD affinity
    const int y  = (blockIdx.x >> 3) & 63;
    const int hf = blockIdx.x >> 9;            // c8 half
    const int c8 = (tid >> 4) + 16 * hf;       // 0..31
    const int x0 = (tid & 15) * 4;             // 4 consecutive x per thread
    const float* p = in2 + b * BSTRIDE + y * 64 + c8 * 8 * CSTRIDE + x0;
    uint4* dst = out16 + (b * 64 + y) * 2048 + c8 * 64 + x0;

    float4 v[8];
#pragma unroll
    for (int j = 0; j < 8; ++j)
        v[j] = *reinterpret_cast<const float4*>(p + j * CSTRIDE);
#pragma unroll
    for (int xi = 0; xi < 4; ++xi) {
        uint4 o;
        o.x = pack_bf2(ELT(v[0], xi), ELT(v[1], xi));
        o.y = pack_bf2(ELT(v[2], xi), ELT(v[3], xi));
        o.z = pack_bf2(ELT(v[4], xi), ELT(v[5], xi));
        o.w = pack_bf2(ELT(v[6], xi), ELT(v[7], xi));
        dst[xi] = o;
    }
}

// ---------------- main correlation kernel (no LDS, no barriers) ----------------
__global__ __launch_bounds__(1024, 4)
void corr_mfma(const float* __restrict__ in1,
               const uint4* __restrict__ in2t,
               float* __restrict__ out)
{
    const int tid  = threadIdx.x;
    const int lane = tid & 63;
    const int w    = tid >> 6;          // wave 0..15
    const int cl   = lane & 15;         // MFMA m/n lane index
    const int q    = lane >> 4;         // MFMA quad
    const int m    = w & 3;             // M-tile: gx in [16m, 16m+16)
    const int d    = w >> 2;            // band offset 0..3
    const int n    = m + d;             // N-tile: col in [16n, 16n+16)
    const int b    = blockIdx.x & 7;    // batch -> XCD affinity
    const int p    = blockIdx.x >> 3;   // 0..31
    const int y0   = 4 * (p >> 1) + (p & 1);   // pair (y0, y0+2), covers all y

    // ---- A fragments for both y's: af[h][k] = in1[b, 32k+8q+j, y0+2h, 16m+cl] ----
    bf16x8 af[2][8];
#pragma unroll
    for (int h = 0; h < 2; ++h) {
        const float* pb = in1 + b * BSTRIDE + (y0 + 2 * h) * 64 + 16 * m + cl
                        + 8 * q * CSTRIDE;
#pragma unroll
        for (int k = 0; k < 8; ++k) {
            const float* pp = pb + 32 * k * CSTRIDE;
            float v[8];
#pragma unroll
            for (int j = 0; j < 8; ++j) v[j] = pp[j * CSTRIDE];
#pragma unroll
            for (int j = 0; j < 4; ++j)
                ((unsigned*)&af[h][k])[j] = pack_bf2(v[2 * j], v[2 * j + 1]);
        }
    }

    const int  x   = 16 * n + cl - 20;               // in2 x (may be OOB)
    const bool xok = (x >= 0) && (x < 64);

    // ---- per-lane store metadata (loop-invariant; ok[] become SGPR masks) ----
    bool ok[4];
    int  obase0[4], obase1[4];
#pragma unroll
    for (int i4 = 0; i4 < 4; ++i4) {
        const int gx = 16 * m + 4 * q + i4;
        const int d2 = 16 * d + cl - 4 * q - i4;
        ok[i4] = (d2 >= 0) && (d2 <= 40) && !(d2 & 1);
        const int dx = ok[i4] ? (d2 >> 1) : 0;       // 0..20, safe when unused
        obase0[i4] = ((b * 441 + dx) * 64 + y0    ) * 64 + gx;
        obase1[i4] = ((b * 441 + dx) * 64 + y0 + 2) * 64 + gx;
    }

    int roff0 = 0;              // r0 = i   -> i * 21 * 4096
    int roff1 = -86016;         // r1 = i-1

    for (int i = 0; i < 22; ++i) {
        const int  yy      = y0 - 20 + 2 * i;
        const bool compute = (yy >= 0) && (yy < 64);
        const bool h0v     = (i <= 20);              // half0 r = i valid
        const bool h1v     = (i >= 1);               // half1 r = i-1 valid

        f32x4 acc0 = {0.f, 0.f, 0.f, 0.f};
        f32x4 acc1 = {0.f, 0.f, 0.f, 0.f};
        if (compute) {
            const uint4* src = in2t + (b * 64 + yy) * 2048 + x;   // + (4k+q)*64
            // two 4-load batches keep <=16 B-regs in flight (af must stay resident)
#pragma unroll
            for (int kb = 0; kb < 2; ++kb) {
                uint4 wv[4];
#pragma unroll
                for (int k4 = 0; k4 < 4; ++k4) {
                    const int k = kb * 4 + k4;
                    const uint4* pk = xok ? (src + (4 * k + q) * 64) : &ZERO16;
                    wv[k4] = *pk;
                }
#pragma unroll
                for (int k4 = 0; k4 < 4; ++k4) {
                    const int k = kb * 4 + k4;
                    const bf16x8 bf = __builtin_bit_cast(bf16x8, wv[k4]);
                    if (h0v) acc0 = __builtin_amdgcn_mfma_f32_16x16x32_bf16(af[0][k], bf, acc0, 0, 0, 0);
                    if (h1v) acc1 = __builtin_amdgcn_mfma_f32_16x16x32_bf16(af[1][k], bf, acc1, 0, 0, 0);
                }
            }
        }

        // ---- direct accumulator stores (acc==0 when !compute => zero-fill) ----
#pragma unroll
        for (int i4 = 0; i4 < 4; ++i4) {
            if (ok[i4]) {
                if (h0v) out[obase0[i4] + roff0] = acc0[i4] * (1.f / 256.f);
                if (h1v) out[obase1[i4] + roff1] = acc1[i4] * (1.f / 256.f);
            }
        }
        roff0 += 86016;
        roff1 += 86016;
    }
}

extern "C" void kernel_launch(void* const* d_in, const int* in_sizes, int n_in,
                              void* d_out, int out_size, void* d_ws, size_t ws_size,
                              hipStream_t stream) {
    const float* in1 = (const float*)d_in[0];
    const float* in2 = (const float*)d_in[1];
    float* out = (float*)d_out;

    conv_in2<<<dim3(1024), dim3(256), 0, stream>>>(in2, (uint4*)d_ws);
    corr_mfma<<<dim3(256), dim3(1024), 0, stream>>>(in1, (const uint4*)d_ws, out);
}

// Round 7
// 154.856 us; speedup vs baseline: 1.1610x; 1.1610x over previous
//
#include <hip/hip_runtime.h>
#include <hip/hip_bf16.h>

// FlowNetC correlation via bf16 MFMA, fp32 accumulate.
// out[b, r*21+dx, y, x] = (1/256) * sum_c in1[b,c,y,x] * in2[b,c, y+2r-20, x+2dx-20]
//
// Round-11 structure: 4-WAVE BLOCKS for load balance + backfill.
//   Ledger: r5 direct-L2 60.5us / r6 stage-1 66.4 / r8 stage-2 67.2 /
//   r9 barrier-free 63.6 / r10 no-LDS stores 84.8 (write scatter, reverted).
//   Every per-iter phase has been ablated; none dominates. Remaining
//   structural cost: grid=256 = EXACTLY 1 block/CU -> no backfill, and
//   block work varies 12..22 compute-iters by y0 (edge blocks skip ~45%);
//   makespan = slowest block, ~25% CU idle (matches Occupancy 30%).
//   Fix: split the 16-wave block by diagonal band d into 4 blocks of 4
//   waves (ownership (m,d) already disjoint -- r9 math). 1024 blocks,
//   4 co-resident/CU (128 regs/wave * 16 waves = full file), scheduler
//   backfills early finishers; co-resident blocks at different phases
//   overlap B-load bursts with MFMA/epilogue. Epilogue = r9's barrier-free
//   wave-private slds patch (same-wave lgkmcnt ordering, no __syncthreads),
//   which keeps stores 64B-coalesced (r10's lesson).
//   dur_us fits 2x(conv+corr) across all rounds -> conv ~13-15us real;
//   corr improvements count double.

typedef short    bf16x8 __attribute__((ext_vector_type(8)));
typedef float    f32x4  __attribute__((ext_vector_type(4)));

constexpr int CSTRIDE = 64 * 64;        // fp32 channel plane
constexpr int BSTRIDE = 256 * CSTRIDE;  // fp32 batch

union BF2 { __hip_bfloat162 h; unsigned u; };

__device__ inline unsigned pack_bf2(float lo, float hi) {
    BF2 cv;
    cv.h = __float22bfloat162_rn(make_float2(lo, hi));
    return cv.u;
}

#define ELT(v4, xi) ((xi) == 0 ? (v4).x : (xi) == 1 ? (v4).y : (xi) == 2 ? (v4).z : (v4).w)

__device__ __align__(16) const uint4 ZERO16 = {0u, 0u, 0u, 0u};

// ---------------- prepass: in2 -> bf16 frag-native chunks ----------------
__global__ __launch_bounds__(256)
void conv_in2(const float* __restrict__ in2, uint4* __restrict__ out16)
{
    const int tid = threadIdx.x;
    const int b  = blockIdx.x & 7;             // XCD affinity
    const int y  = (blockIdx.x >> 3) & 63;
    const int hf = blockIdx.x >> 9;            // c8 half
    const int c8 = (tid >> 4) + 16 * hf;       // 0..31
    const int x0 = (tid & 15) * 4;             // 4 consecutive x per thread
    const float* p = in2 + b * BSTRIDE + y * 64 + c8 * 8 * CSTRIDE + x0;
    uint4* dst = out16 + (b * 64 + y) * 2048 + c8 * 64 + x0;

    float4 v[8];
#pragma unroll
    for (int j = 0; j < 8; ++j)
        v[j] = *reinterpret_cast<const float4*>(p + j * CSTRIDE);
#pragma unroll
    for (int xi = 0; xi < 4; ++xi) {
        uint4 o;
        o.x = pack_bf2(ELT(v[0], xi), ELT(v[1], xi));
        o.y = pack_bf2(ELT(v[2], xi), ELT(v[3], xi));
        o.z = pack_bf2(ELT(v[4], xi), ELT(v[5], xi));
        o.w = pack_bf2(ELT(v[6], xi), ELT(v[7], xi));
        dst[xi] = o;
    }
}

// ---------------- main correlation kernel (4 waves/block, no barriers) --------
__global__ __launch_bounds__(256, 4)
void corr_mfma(const float* __restrict__ in1,
               const uint4* __restrict__ in2t,
               float* __restrict__ out)
{
    // per-wave private scratch: [wave][half][d2/2][gx_local(padded)]
    __shared__ float slds[4][2][21][17];   // 11.4 KB/block

    const int tid  = threadIdx.x;
    const int lane = tid & 63;
    const int w    = tid >> 6;          // wave 0..3
    const int cl   = lane & 15;         // MFMA m/n lane index
    const int q    = lane >> 4;         // MFMA quad
    const int m    = w;                 // M-tile: gx in [16m, 16m+16)
    const int b    = blockIdx.x & 7;    // batch -> XCD affinity
    const int p    = (blockIdx.x >> 3) & 31;   // 0..31
    const int d    = blockIdx.x >> 8;   // band offset 0..3 (block-uniform)
    const int n    = m + d;             // N-tile: col in [16n, 16n+16)
    const int y0   = 4 * (p >> 1) + (p & 1);   // pair (y0, y0+2), covers all y

    // ---- A fragments for both y's: af[h][k] = in1[b, 32k+8q+j, y0+2h, 16m+cl] ----
    bf16x8 af[2][8];
#pragma unroll
    for (int h = 0; h < 2; ++h) {
        const float* pb = in1 + b * BSTRIDE + (y0 + 2 * h) * 64 + 16 * m + cl
                        + 8 * q * CSTRIDE;
#pragma unroll
        for (int k = 0; k < 8; ++k) {
            const float* pp = pb + 32 * k * CSTRIDE;
            float v[8];
#pragma unroll
            for (int j = 0; j < 8; ++j) v[j] = pp[j * CSTRIDE];
#pragma unroll
            for (int j = 0; j < 4; ++j)
                ((unsigned*)&af[h][k])[j] = pack_bf2(v[2 * j], v[2 * j + 1]);
        }
    }

    const int  x   = 16 * n + cl - 20;               // in2 x (may be OOB)
    const bool xok = (x >= 0) && (x < 64);

    // band d2-range of this block (even values): [lo_e, hi_e]  (block-uniform)
    const int lo_e = (d == 0) ? 0 : 16 * d - 14;              // 0, 2, 18, 34
    const int hi_e = (16 * d + 14 > 40) ? 40 : 16 * d + 14;   // 14, 30, 40, 40
    const int cnt    = ((hi_e - lo_e) >> 1) + 1;              // 8, 15, 12, 4
    const int rounds = (cnt + 3) >> 2;                        // 2, 4, 3, 1

    float* ms = &slds[w][0][0][0];      // [h*357 + (d2>>1)*17 + gxl]

    const int s   = lane >> 4;          // segment slot 0..3 in store rounds
    const int pos = lane & 15;          // gx_local in store rounds

    for (int i = 0; i < 22; ++i) {
        const int  yy      = y0 - 20 + 2 * i;
        const bool compute = (yy >= 0) && (yy < 64);
        const bool h0v     = (i <= 20);                // half0 r = i valid
        const bool h1v     = (i >= 1);                 // half1 r = i-1 valid

        if (compute) {
            f32x4 acc0 = {0.f, 0.f, 0.f, 0.f};
            f32x4 acc1 = {0.f, 0.f, 0.f, 0.f};
            const uint4* src = in2t + (b * 64 + yy) * 2048 + x;   // + (4k+q)*64
            // two 4-load batches keep <=16 B-regs in flight (af must stay resident)
#pragma unroll
            for (int kb = 0; kb < 2; ++kb) {
                uint4 wv[4];
#pragma unroll
                for (int k4 = 0; k4 < 4; ++k4) {
                    const int k = kb * 4 + k4;
                    const uint4* pk = xok ? (src + (4 * k + q) * 64) : &ZERO16;
                    wv[k4] = *pk;
                }
#pragma unroll
                for (int k4 = 0; k4 < 4; ++k4) {
                    const int k = kb * 4 + k4;
                    const bf16x8 bf = __builtin_bit_cast(bf16x8, wv[k4]);
                    if (h0v) acc0 = __builtin_amdgcn_mfma_f32_16x16x32_bf16(af[0][k], bf, acc0, 0, 0, 0);
                    if (h1v) acc1 = __builtin_amdgcn_mfma_f32_16x16x32_bf16(af[1][k], bf, acc1, 0, 0, 0);
                }
            }
            // wave-local diagonal scatter: elem (cl,q,i4) -> (d2, gxl=4q+i4)
#pragma unroll
            for (int i4 = 0; i4 < 4; ++i4) {
                const int gxl = 4 * q + i4;
                const int d2  = 16 * d + cl - gxl;
                if (d2 >= 0 && d2 <= 40 && !(d2 & 1)) {
                    const int off = (d2 >> 1) * 17 + gxl;
                    if (h0v) ms[off]       = acc0[i4];
                    if (h1v) ms[357 + off] = acc1[i4];
                }
            }
        }

        // wave-local read-back + segment stores (same-wave ds_write -> ds_read
        // ordering via compiler lgkmcnt; no barrier needed)
        for (int rd = 0; rd < rounds; ++rd) {
            const int d2 = lo_e + 2 * (rd * 4 + s);
            const int al = (16 * d > d2) ? (16 * d - d2) : 0;
            int bl = 16 * d + 16 - d2; if (bl > 16) bl = 16;
            const bool act = (d2 <= hi_e) && (pos >= al) && (pos < bl);
            if (act) {
                const int off = (d2 >> 1) * 17 + pos;
                const int gx  = 16 * m + pos;
                if (h0v) {
                    const float v = compute ? ms[off] * (1.f / 256.f) : 0.f;
                    out[((b * 441 + i * 21 + (d2 >> 1)) * 64 + y0) * 64 + gx] = v;
                }
                if (h1v) {
                    const float v = compute ? ms[357 + off] * (1.f / 256.f) : 0.f;
                    out[((b * 441 + (i - 1) * 21 + (d2 >> 1)) * 64 + (y0 + 2)) * 64 + gx] = v;
                }
            }
        }
    }
}

extern "C" void kernel_launch(void* const* d_in, const int* in_sizes, int n_in,
                              void* d_out, int out_size, void* d_ws, size_t ws_size,
                              hipStream_t stream) {
    const float* in1 = (const float*)d_in[0];
    const float* in2 = (const float*)d_in[1];
    float* out = (float*)d_out;

    conv_in2<<<dim3(1024), dim3(256), 0, stream>>>(in2, (uint4*)d_ws);
    corr_mfma<<<dim3(1024), dim3(256), 0, stream>>>(in1, (const uint4*)d_ws, out);
}